// Round 10
// baseline (162.437 us; speedup 1.0000x reference)
//
#include <hip/hip_runtime.h>

// NodeEncoder with interpolation, round 10.
//
// Dead: nt-stores (R3), per-wave MLP (R4), barrier drain (R7, null),
// stream topology / occupancy (R9, null: 2 waves/SIMD == 32 waves/CU perf).
// Confirmed: phase separation (R5). Plateau: ~5.0 TB/s.
//
// R10 theory: the last structural difference vs the 6.29 TB/s copy kernel
// (which is MORE read-heavy than us and still faster) is LDS in the store
// data path. This round: NO LDS at all. One atom per lane; z loaded
// coalesced (4 B/lane); the 16-value row computed in registers via the
// branchless chain (~115 VALU/atom = 71 B/cyc/CU capacity, 9x the 7.6
// B/cyc/CU HBM requirement -- unlike R1 which ran 4 chains/atom); row
// stored as 4 x float4. Per-instruction stores are 64 B-strided, but the
// wave's 4 stores cover one contiguous 4 KB span back-to-back -> L2
// write-combine merges full lines. Exact grid, no loop (fill-like).

#define K_TAB 16

typedef float v4f __attribute__((ext_vector_type(4)));

__global__ __launch_bounds__(256) void node_encode_kernel(
    const float* __restrict__ z_in,
    float* __restrict__ out,
    int n_atoms)
{
    const int atom = blockIdx.x * 256 + threadIdx.x;
    if (atom >= n_atoms) return;

    constexpr float ZS0 = 0.f,  ZS1 = 1.f,  ZS2 = 6.f,  ZS3 = 7.f;
    constexpr float ZS4 = 8.f,  ZS5 = 11.f, ZS6 = 13.f, ZS7 = 14.f;
    constexpr float ZS8 = 16.f, ZS9 = 17.f, ZS10 = 26.f, ZS11 = 29.f;
    constexpr float ZS12 = 47.f, ZS13 = 78.f, ZS14 = 79.f, ZS15 = 83.f;

    const float z = z_in[atom];          // coalesced 4 B/lane

    // j = #entries < z (searchsorted-left); zlo = largest entry < z;
    // zhi = smallest entry >= z.
    int j = 0;
    float zlo = ZS0;
    float zhi = ZS15;

#define STEP_LO(c) { const bool lt = ((c) < z); j += lt ? 1 : 0; zlo = lt ? (c) : zlo; }
    STEP_LO(ZS0)  STEP_LO(ZS1)  STEP_LO(ZS2)  STEP_LO(ZS3)
    STEP_LO(ZS4)  STEP_LO(ZS5)  STEP_LO(ZS6)  STEP_LO(ZS7)
    STEP_LO(ZS8)  STEP_LO(ZS9)  STEP_LO(ZS10) STEP_LO(ZS11)
    STEP_LO(ZS12) STEP_LO(ZS13) STEP_LO(ZS14) STEP_LO(ZS15)
#undef STEP_LO

#define STEP_HI(c) { zhi = ((c) >= z) ? (c) : zhi; }
    STEP_HI(ZS14) STEP_HI(ZS13) STEP_HI(ZS12) STEP_HI(ZS11)
    STEP_HI(ZS10) STEP_HI(ZS9)  STEP_HI(ZS8)  STEP_HI(ZS7)
    STEP_HI(ZS6)  STEP_HI(ZS5)  STEP_HI(ZS4)  STEP_HI(ZS3)
    STEP_HI(ZS2)  STEP_HI(ZS1)  STEP_HI(ZS0)
#undef STEP_HI

    if (j > K_TAB - 1) j = K_TAB - 1;

    const bool exact = (zhi == z);
    const float denom = exact ? 1.f : (zhi - zlo);
    const float inv   = 1.f / denom;
    const float whi   = exact ? 1.f : (z - zlo) * inv;
    const float wlo   = exact ? 0.f : (zhi - z) * inv;
    int jl = j - (exact ? 0 : 1);
    if (jl < 0) jl = 0;

    // materialize the 16-value row in registers (all static indices)
    v4f q0, q1, q2, q3;
#define ELT(c) ((c) == j ? whi : 0.f) + ((c) == jl ? wlo : 0.f)
    q0.x = ELT(0);  q0.y = ELT(1);  q0.z = ELT(2);  q0.w = ELT(3);
    q1.x = ELT(4);  q1.y = ELT(5);  q1.z = ELT(6);  q1.w = ELT(7);
    q2.x = ELT(8);  q2.y = ELT(9);  q2.z = ELT(10); q2.w = ELT(11);
    q3.x = ELT(12); q3.y = ELT(13); q3.z = ELT(14); q3.w = ELT(15);
#undef ELT

    v4f* __restrict__ o = reinterpret_cast<v4f*>(out) + (long)atom * 4;
    o[0] = q0;
    o[1] = q1;
    o[2] = q2;
    o[3] = q3;
}

extern "C" void kernel_launch(void* const* d_in, const int* in_sizes, int n_in,
                              void* d_out, int out_size, void* d_ws, size_t ws_size,
                              hipStream_t stream) {
    const float* z = (const float*)d_in[0];
    float* out = (float*)d_out;
    const int n_atoms = in_sizes[0];

    const int block = 256;
    const int grid = (n_atoms + block - 1) / block;   // one atom per thread

    node_encode_kernel<<<grid, block, 0, stream>>>(z, out, n_atoms);
}

// Round 11
// 104.977 us; speedup vs baseline: 1.5474x; 1.5474x over previous
//
#include <hip/hip_runtime.h>

// NodeEncoder with interpolation, round 11.
//
// Ledger — dead: nt-stores (R3 -12%), per-wave MLP (R4 -7%), barrier drain
// (R7 null), 8-waves/CU topology (R9 null), no-LDS strided stores (R10 -48%:
// per-instruction store contiguity is essential). Confirmed: phase-separated
// prefetched reads (R5 +11%), LDS LUT-gather for contiguous stores.
//
// R11: mimic the 6.9 TB/s fill kernel's regime exactly — ~4 waves/CU, ZERO
// synchronization, one global forward-sweeping store stream — while keeping
// everything confirmed-good:
//   - 64-thread blocks (1 wave), 1024 blocks = 4 waves/CU. No __syncthreads
//     ANYWHERE (single wave owns its buffers; compiler lgkmcnt orders LDS).
//   - per-wave chunk = 256 atoms: stage 1 KB z to LDS, 16 x (zi -> LUT
//     ds_read_b128 -> 1 KB contiguous wave-store). 16 KB out per chunk.
//   - chunks round-robin over waves (c += nwaves): chip-wide forward sweep.
//   - next chunk's z prefetched into registers under the store run (R5 win).

#define K_TAB 16
#define N_Z   83
#define WSZ   64
#define CA    256                  // atoms per wave-chunk (1 KB z, 16 KB out)
#define INNER (CA / 16)            // 16 store iterations per chunk

typedef float v4f __attribute__((ext_vector_type(4)));

__global__ __launch_bounds__(WSZ) void node_encode_kernel(
    const float* __restrict__ z_in,
    float* __restrict__ out,
    int n_atoms, int n_chunks)
{
    __shared__ float lut[N_Z][K_TAB];   // 5.3 KB
    __shared__ float zl[2][CA];         // 2 x 1 KB, single-wave owned

    const int lane = threadIdx.x;       // one wave per block

    // ---- LUT init: rows lane and lane+64 (single wave, no barrier needed) ----
    constexpr float tab[K_TAB] = {0.f, 1.f, 6.f, 7.f, 8.f, 11.f, 13.f, 14.f,
                                  16.f, 17.f, 26.f, 29.f, 47.f, 78.f, 79.f, 83.f};
    for (int row = lane; row < N_Z; row += WSZ) {
        const float zf = (float)row;
        int j = 0;
        float zlo = tab[0];
        float zhi = tab[K_TAB - 1];
#pragma unroll
        for (int k = 0; k < K_TAB; ++k) {          // ascending: count < z, track z_lo
            const bool lt = (tab[k] < zf);
            j += lt ? 1 : 0;
            zlo = lt ? tab[k] : zlo;
        }
#pragma unroll
        for (int k = K_TAB - 2; k >= 0; --k) {     // descending: smallest entry >= z
            zhi = (tab[k] >= zf) ? tab[k] : zhi;
        }
        const bool exact = (zhi == zf);
        const float denom = exact ? 1.f : (zhi - zlo);
        const float inv   = 1.f / denom;
        const float whi   = exact ? 1.f : (zf - zlo) * inv;
        const float wlo   = exact ? 0.f : (zhi - zf) * inv;
        int jl = j - (exact ? 0 : 1);
        if (jl < 0) jl = 0;
#pragma unroll
        for (int c = 0; c < K_TAB; ++c) {
            lut[row][c] = (c == j ? whi : 0.f) + (c == jl ? wlo : 0.f);
        }
    }

    v4f* __restrict__ out4 = reinterpret_cast<v4f*>(out);
    const int nwaves = gridDim.x;       // 1 wave per block
    const int gwave  = blockIdx.x;

    // ---- prologue: load first chunk's z into registers ----
    int c = gwave;
    v4f zreg = {0.f, 0.f, 0.f, 0.f};
    if (c < n_chunks) {
        const int a0 = c * CA + lane * 4;          // CA*n_chunks <= ~8M: no overflow
        if (a0 + 3 < n_atoms) {
            zreg = *reinterpret_cast<const v4f*>(&z_in[a0]);
        } else {
#pragma unroll
            for (int e = 0; e < 4; ++e)
                if (a0 + e < n_atoms) zreg[e] = z_in[a0 + e];
        }
    }

    // ---- zero-barrier phase loop ----
    int p = 0;
    for (; c < n_chunks; c += nwaves, ++p) {
        // publish current chunk's z (wave-private buffer; lgkmcnt orders RAW)
        *reinterpret_cast<v4f*>(&zl[p & 1][lane * 4]) = zreg;

        // prefetch next chunk's z under the store run
        const int cn = c + nwaves;
        if (cn < n_chunks) {
            const int a0 = cn * CA + lane * 4;
            if (a0 + 3 < n_atoms) {
                zreg = *reinterpret_cast<const v4f*>(&z_in[a0]);
            } else {
                v4f zt = {0.f, 0.f, 0.f, 0.f};
#pragma unroll
                for (int e = 0; e < 4; ++e)
                    if (a0 + e < n_atoms) zt[e] = z_in[a0 + e];
                zreg = zt;
            }
        }

        const float* __restrict__ zb = zl[p & 1];
        const long base4 = (long)c * (CA * 4);     // float4 index of chunk start
        if ((c + 1) * CA <= n_atoms) {
            // full chunk: 16 x (zi -> lut b128 -> contiguous 1 KB wave-store)
#pragma unroll
            for (int k = 0; k < INNER; ++k) {
                const int u  = k * WSZ + lane;
                const int zi = (int)zb[u >> 2];
                const v4f v  = *reinterpret_cast<const v4f*>(&lut[zi][(u & 3) << 2]);
                out4[base4 + u] = v;
            }
        } else {
            const long total4 = (long)n_atoms * 4;
            for (int k = 0; k < INNER; ++k) {
                const int u = k * WSZ + lane;
                const long g = base4 + u;
                if (g < total4) {
                    const int zi = (int)zb[u >> 2];
                    out4[g] = *reinterpret_cast<const v4f*>(&lut[zi][(u & 3) << 2]);
                }
            }
        }
    }
}

extern "C" void kernel_launch(void* const* d_in, const int* in_sizes, int n_in,
                              void* d_out, int out_size, void* d_ws, size_t ws_size,
                              hipStream_t stream) {
    const float* z = (const float*)d_in[0];
    float* out = (float*)d_out;
    const int n_atoms = in_sizes[0];

    const int n_chunks = (n_atoms + CA - 1) / CA;   // 31250 for 8M atoms
    const int grid = 1024;                          // 4 single-wave blocks/CU

    node_encode_kernel<<<grid, WSZ, 0, stream>>>(z, out, n_atoms, n_chunks);
}